// Round 6
// baseline (160.606 us; speedup 1.0000x reference)
//
#include <hip/hip_runtime.h>

#define BATCH 8
#define CCH 8
#define HW 262144       // 512*512
#define SEGS 16         // segments 1..16 (segment 0 is provably ignored by the reference)
#define XB 64           // blocks per batch; grid (64,8) = 512 blocks = 2/CU
#define GPB (HW / 4 / XB)   // 1024 int4-groups per block
#define NITER (GPB / 256)   // 4 groups per thread

// ws float layout (NO atomics anywhere; every slot written before read):
//   P1    = 0     : [8][64][144] per-block partials: cnt[16], sums[s*8+c] (128)
//   MEANS = 73728 : [8][144]     batch-reduced cnt[16] + raw sums[128] (written by pull xb==0)
//   PP    = 74880 : [8][64][16]  per-block pull-penalty partials
#define P1 0
#define MEANS 73728
#define PP 74880

// ---------------------------------------------------------------------------
// Pass 1: counts + per-channel sums.
// KEY CHANGE vs R5: __builtin_amdgcn_sched_barrier(0) between the 10-load
// batch and its uses. The pre-RA scheduler has sunk the loads into the use
// chain in every previous round (VGPR_Count 24-28 proves it), leaving ~1
// outstanding load/wave -> ~1.5 TB/s effective. The barrier forces all 10
// loads to ISSUE first (10 KB in flight per wave), at a cost of ~60 VGPRs.
// ---------------------------------------------------------------------------
__global__ __launch_bounds__(256) void accum_kernel(
    const float* __restrict__ emb, const int* __restrict__ lab,
    const int* __restrict__ msk, float* __restrict__ ws)
{
    const int b = blockIdx.y, xb = blockIdx.x;
    const int tid = threadIdx.x, wave = tid >> 6;
    __shared__ float lsum[4][SEGS][CCH];
    __shared__ float lcnt[4][SEGS];
    for (int i = tid; i < 4 * SEGS * CCH; i += 256) (&lsum[0][0][0])[i] = 0.f;
    for (int i = tid; i < 4 * SEGS; i += 256) (&lcnt[0][0])[i] = 0.f;
    __syncthreads();

    const int4* lb = (const int4*)(lab + (size_t)b * HW);
    const int4* mb = (const int4*)(msk + (size_t)b * HW);
    const float4* ep = (const float4*)(emb + (size_t)b * CCH * HW);
    const int base = xb * GPB;

#pragma unroll
    for (int q = 0; q < NITER; ++q) {
        const int g = base + q * 256 + tid;
        // ---- batched loads: must all issue before any use ----
        int4 l4 = lb[g];
        int4 m4 = mb[g];
        float4 e[CCH];
#pragma unroll
        for (int c = 0; c < CCH; ++c) e[c] = ep[(size_t)c * (HW / 4) + g];
        __builtin_amdgcn_sched_barrier(0);   // nothing crosses: loads stay hoisted

        const int id0 = m4.x ? l4.x : 0;
        const int id1 = m4.y ? l4.y : 0;
        const int id2 = m4.z ? l4.z : 0;
        const int id3 = m4.w ? l4.w : 0;
        if (id0) atomicAdd(&lcnt[wave][id0 - 1], 1.f);
        if (id1) atomicAdd(&lcnt[wave][id1 - 1], 1.f);
        if (id2) atomicAdd(&lcnt[wave][id2 - 1], 1.f);
        if (id3) atomicAdd(&lcnt[wave][id3 - 1], 1.f);
#pragma unroll
        for (int c = 0; c < CCH; ++c) {
            if (id0) atomicAdd(&lsum[wave][id0 - 1][c], e[c].x);
            if (id1) atomicAdd(&lsum[wave][id1 - 1][c], e[c].y);
            if (id2) atomicAdd(&lsum[wave][id2 - 1][c], e[c].z);
            if (id3) atomicAdd(&lsum[wave][id3 - 1][c], e[c].w);
        }
    }
    __syncthreads();

    float* dst = ws + P1 + (b * XB + xb) * 144;
    if (tid < SEGS)
        dst[tid] = lcnt[0][tid] + lcnt[1][tid] + lcnt[2][tid] + lcnt[3][tid];
    if (tid < SEGS * CCH)
        dst[16 + tid] = (&lsum[0][0][0])[tid] + (&lsum[1][0][0])[tid]
                      + (&lsum[2][0][0])[tid] + (&lsum[3][0][0])[tid];
}

// ---------------------------------------------------------------------------
// Pass 2: pull penalties. Same sched_barrier treatment on the load batch.
// ---------------------------------------------------------------------------
__global__ __launch_bounds__(256) void pull_kernel(
    const float* __restrict__ emb, const int* __restrict__ lab,
    const int* __restrict__ msk, float* __restrict__ ws)
{
    const int b = blockIdx.y, xb = blockIdx.x;
    const int tid = threadIdx.x, wave = tid >> 6;
    __shared__ float sred[144];       // reduced cnt[16] + sums[128] for batch b
    __shared__ float mt[CCH][SEGS];   // transposed means
    __shared__ float lpen[4][SEGS];

    // batch-reduce the 64 partials (threads 0..143; independent loads, ILP)
    if (tid < 144) {
        const float* p = ws + P1 + (size_t)b * XB * 144 + tid;
        float acc = 0.f;
#pragma unroll 8
        for (int k = 0; k < XB; ++k) acc += p[k * 144];
        sred[tid] = acc;
        if (xb == 0) ws[MEANS + b * 144 + tid] = acc;   // persist for finalize
    }
    if (tid >= 144 && tid < 144 + 64) (&lpen[0][0])[tid - 144] = 0.f;
    __syncthreads();
    if (tid < SEGS * CCH) {
        int s = tid & (SEGS - 1);
        int c = tid >> 4;
        mt[c][s] = sred[16 + s * CCH + c] / fmaxf(sred[s], 1.0f);
    }
    __syncthreads();

    const int4* lb = (const int4*)(lab + (size_t)b * HW);
    const int4* mb = (const int4*)(msk + (size_t)b * HW);
    const float4* ep = (const float4*)(emb + (size_t)b * CCH * HW);
    const int base = xb * GPB;

#pragma unroll
    for (int q = 0; q < NITER; ++q) {
        const int g = base + q * 256 + tid;
        // ---- batched loads: must all issue before any use ----
        int4 l4 = lb[g];
        int4 m4 = mb[g];
        float4 e[CCH];
#pragma unroll
        for (int c = 0; c < CCH; ++c) e[c] = ep[(size_t)c * (HW / 4) + g];
        __builtin_amdgcn_sched_barrier(0);   // nothing crosses: loads stay hoisted

        const int id0 = m4.x ? l4.x : 0;
        const int id1 = m4.y ? l4.y : 0;
        const int id2 = m4.z ? l4.z : 0;
        const int id3 = m4.w ? l4.w : 0;
        const int ix0 = id0 ? id0 - 1 : 0;
        const int ix1 = id1 ? id1 - 1 : 0;
        const int ix2 = id2 ? id2 - 1 : 0;
        const int ix3 = id3 ? id3 - 1 : 0;

        float ss0 = 0.f, ss1 = 0.f, ss2 = 0.f, ss3 = 0.f;
#pragma unroll
        for (int c = 0; c < CCH; ++c) {
            float d0 = e[c].x - mt[c][ix0];
            float d1 = e[c].y - mt[c][ix1];
            float d2 = e[c].z - mt[c][ix2];
            float d3 = e[c].w - mt[c][ix3];
            ss0 = fmaf(d0, d0, ss0);
            ss1 = fmaf(d1, d1, ss1);
            ss2 = fmaf(d2, d2, ss2);
            ss3 = fmaf(d3, d3, ss3);
        }
        if (id0) { float d = sqrtf(fmaxf(ss0, 1e-12f)); float h = fmaxf(d - 0.5f, 0.f); atomicAdd(&lpen[wave][ix0], h * h); }
        if (id1) { float d = sqrtf(fmaxf(ss1, 1e-12f)); float h = fmaxf(d - 0.5f, 0.f); atomicAdd(&lpen[wave][ix1], h * h); }
        if (id2) { float d = sqrtf(fmaxf(ss2, 1e-12f)); float h = fmaxf(d - 0.5f, 0.f); atomicAdd(&lpen[wave][ix2], h * h); }
        if (id3) { float d = sqrtf(fmaxf(ss3, 1e-12f)); float h = fmaxf(d - 0.5f, 0.f); atomicAdd(&lpen[wave][ix3], h * h); }
    }
    __syncthreads();
    if (tid < SEGS)
        ws[PP + (b * XB + xb) * 16 + tid] =
            lpen[0][tid] + lpen[1][tid] + lpen[2][tid] + lpen[3][tid];
}

// ---------------------------------------------------------------------------
// Pass 3: finalize (unchanged, verified)
// ---------------------------------------------------------------------------
__global__ __launch_bounds__(256) void finalize_kernel(
    const float* __restrict__ ws, float* __restrict__ out)
{
    __shared__ float cnt[BATCH][SEGS];
    __shared__ float mu[BATCH][SEGS][CCH];
    __shared__ float pen[BATCH][SEGS];
    __shared__ float res[BATCH][3];

    for (int i = threadIdx.x; i < BATCH * 144; i += 256) {
        int bb = i / 144, t = i - bb * 144;
        float v = ws[MEANS + i];
        if (t < SEGS) cnt[bb][t] = v;
        else {
            int idx = t - 16;                  // s*8 + c
            mu[bb][idx >> 3][idx & 7] = v;     // raw sum for now
        }
    }
    if (threadIdx.x < BATCH * SEGS) {
        int bb = threadIdx.x >> 4, s = threadIdx.x & 15;
        const float* p = ws + PP + (size_t)bb * XB * 16 + s;
        float acc = 0.f;
#pragma unroll 8
        for (int k = 0; k < XB; ++k) acc += p[k * 16];
        pen[bb][s] = acc;
    }
    __syncthreads();
    for (int i = threadIdx.x; i < BATCH * SEGS * CCH; i += 256) {
        int bb = i >> 7, r = i & 127;
        mu[bb][r >> 3][r & 7] /= fmaxf(cnt[bb][r >> 3], 1.0f);
    }
    __syncthreads();

    const int b = threadIdx.x >> 5;   // 8 batches x 32-lane groups
    const int l = threadIdx.x & 31;

    float pullv = 0.f, Kf = 0.f;
    if (l < SEGS && cnt[b][l] > 0.f) {
        Kf = 1.f;
        pullv = pen[b][l] / cnt[b][l];       // count>0 => max(count,1)=count
    }
    float hs = 0.f, np = 0.f;
    for (int p = l; p < 256; p += 32) {
        int i = p >> 4, j = p & 15;
        if (i < j && cnt[b][i] > 0.f && cnt[b][j] > 0.f) {
            float ssq = 0.f;
#pragma unroll
            for (int c = 0; c < CCH; ++c) {
                float d = mu[b][i][c] - mu[b][j][c];
                ssq += d * d;
            }
            float dist = sqrtf(fmaxf(ssq, 1e-12f));
            float h = fmaxf(3.0f - dist, 0.f);   // 2*DELTA_D = 3.0
            hs += h * h;
            np += 1.f;
        }
    }
#pragma unroll
    for (int m = 16; m >= 1; m >>= 1) {
        pullv += __shfl_xor(pullv, m);
        Kf    += __shfl_xor(Kf, m);
        hs    += __shfl_xor(hs, m);
        np    += __shfl_xor(np, m);
    }
    if (l == 0) {
        res[b][0] = (Kf > 0.f) ? pullv / Kf : 0.f;
        res[b][1] = (np > 0.f) ? hs / np : 0.f;
        res[b][2] = (Kf > 0.f) ? 1.f : 0.f;
    }
    __syncthreads();
    if (threadIdx.x == 0) {
        float sp = 0.f, sh = 0.f, nv = 0.f;
        for (int bb = 0; bb < BATCH; ++bb) {
            sp += res[bb][0] * res[bb][2];
            sh += res[bb][1] * res[bb][2];
            nv += res[bb][2];
        }
        nv = fmaxf(nv, 1.f);
        out[0] = sp / nv;
        out[1] = sh / nv;
    }
}

extern "C" void kernel_launch(void* const* d_in, const int* in_sizes, int n_in,
                              void* d_out, int out_size, void* d_ws, size_t ws_size,
                              hipStream_t stream)
{
    const float* emb = (const float*)d_in[0];
    const int* lab = (const int*)d_in[1];
    const int* msk = (const int*)d_in[2];
    float* out = (float*)d_out;
    float* ws = (float*)d_ws;

    // no memset needed: every ws slot is written before it is read
    dim3 grid(XB, BATCH);
    accum_kernel<<<grid, 256, 0, stream>>>(emb, lab, msk, ws);
    pull_kernel<<<grid, 256, 0, stream>>>(emb, lab, msk, ws);
    finalize_kernel<<<1, 256, 0, stream>>>(ws, out);
}